// Round 4
// baseline (289.476 us; speedup 1.0000x reference)
//
#include <hip/hip_runtime.h>
#include <hip/hip_bf16.h>

#define BB 32
#define HH 56
#define WW 56
#define CC 256
#define NPIX (BB*HH*WW)   // 100352
#define EPS 1e-5f

typedef short bf16x8 __attribute__((ext_vector_type(8)));   // 8 bf16 = 4 VGPRs
typedef float f32x4  __attribute__((ext_vector_type(4)));
typedef unsigned int u32;

__device__ __forceinline__ unsigned short f2bf(float f) {
    __hip_bfloat16 h = __float2bfloat16(f);
    return *reinterpret_cast<unsigned short*>(&h);
}

// async global->LDS DMA, 16B per lane; LDS dest = uniform base + lane*16
__device__ __forceinline__ void dma16(const float* g, void* l) {
    __builtin_amdgcn_global_load_lds(
        (const __attribute__((address_space(1))) void*)g,
        (__attribute__((address_space(3))) void*)l, 16, 0, 0);
}

// ws layout:
//   float stats[512]   : byte 0      (sum[256], sumsq[256])  -- zeroed by memsetAsync
//   float ss[512]      : byte 2048   (scale[256], shift[256])
//   bf16  y[B*H*W*256] : byte 4096   (51.4 MB)

// Grouped conv via bf16 MFMA, double-buffered global_load_lds pipeline.
// Block = (group-pair gp, batch b); loops over 7 row-bands of 8 output rows.
// fp32 tile in LDS: 4 ci4-planes x 10 rows x 58 cols x 16B slots (37120 B),
// slot s=(plane*580+row*58+col) filled by DMA inst I=s/64, lane=s%64.
// Per iter: barrier (waits DMA for this band), issue DMA for next band into
// the other buffer (stays in flight across the whole compute phase), compute.
__global__ __launch_bounds__(256, 2) void k1_conv(
    const float* __restrict__ x, const float* __restrict__ wgt,
    __hip_bfloat16* __restrict__ y, float* __restrict__ stats)
{
    __shared__ float xb[2][4*580*4];        // 2 x 37120 B fp32 tile buffers
    __shared__ unsigned short wb[16*160];   // B-frag-major weights (5 KB)
    __shared__ float bsum[16], bsq[16];

    const int gp   = blockIdx.x;            // group pair 0..15
    const int b    = blockIdx.y;            // batch image
    const int t    = threadIdx.x;
    const int lane = t & 63;
    const int wv   = t >> 6;

    if (t < 16) { bsum[t] = 0.f; bsq[t] = 0.f; }

    // ---- stage weights (once per block): wb[n*160+kk], kk = g*80+tap*8+ci
    {
        const int n  = t >> 4;
        const int k0 = t & 15;
        #pragma unroll
        for (int j = 0; j < 10; ++j) {
            const int kk = k0 + j*16;
            const int g  = (kk >= 80);
            const int r  = kk - g*80;
            const int tap = r >> 3, ci = r & 7;
            unsigned short val = 0;
            if (tap < 9 && (n >> 3) == g)
                val = f2bf(wgt[(tap*8 + ci)*CC + gp*16 + n]);
            wb[n*160 + kk] = val;
        }
    }

    // ---- zero halo columns (col 0 and 57, every plane-row, both buffers)
    if (t < 160) {
        int bi = (t >= 80);
        int i  = t - bi*80;
        int plane = i / 20;
        int rem = i - plane*20;
        int row = rem >> 1;
        int col = (rem & 1) ? 57 : 0;
        *(f32x4*)&xb[bi][(plane*580 + row*58 + col)*4] = (f32x4){0.f,0.f,0.f,0.f};
    }

    // ---- per-lane DMA precompute: 37 insts (waves 0-2: 10, wave 3: 7)
    const int nj = (wv < 3) ? 10 : 7;
    int goff[10];
    int mmid = 0, mfirst = 0, mlast = 0;
    #pragma unroll
    for (int j = 0; j < 10; ++j) {
        int I = wv*10 + j;
        int slot = I*64 + lane;
        int plane = slot / 580;
        int rem  = slot - plane*580;
        int row  = rem / 58;
        int col  = rem - row*58;
        goff[j] = ((row - 1)*WW + (col - 1))*CC + plane*4;   // elements, band 0
        bool colok = (plane < 4) && (col >= 1) && (col <= 56);
        if (colok) {
            mmid |= 1 << j;
            if (row >= 1) mfirst |= 1 << j;   // band 0: row 0 is OOB (h=-1)
            if (row <= 8) mlast  |= 1 << j;   // band 6: row 9 is OOB (h=56)
        }
    }
    const int xbase  = (b*HH*WW)*CC + gp*16;
    const int wvu10  = __builtin_amdgcn_readfirstlane(wv) * 10;

    // ---- prefetch band 0 into buf0 + zero its row 0 (cols 1..56)
    #pragma unroll
    for (int j = 0; j < 10; ++j)
        if (j < nj && ((mfirst >> j) & 1))
            dma16(x + xbase + goff[j], (char*)&xb[0][0] + (wvu10 + j)*1024);
    if (t < 224) {
        int plane = t / 56;
        int col = t - plane*56 + 1;
        *(f32x4*)&xb[0][(plane*580 + col)*4] = (f32x4){0.f,0.f,0.f,0.f};
    }

    // ---- per-lane fragment geometry
    const int n    = lane & 15;           // out-ch within pair / C col
    const int q    = lane >> 4;           // quad
    const int mm   = lane & 15;           // A row (pixel in 2x8 tile)
    const int rowr = wv*2 + (mm >> 3);    // output row within band (0..7)
    const int colb = mm & 7;
    int aoffB[5];                          // byte offset of lo-half per K-step
    #pragma unroll
    for (int s = 0; s < 5; ++s) {
        int o  = s*4 + q;                 // octet 0..19
        int g  = (o >= 10);
        int tp = o - g*10;
        if (tp == 9) tp = 0;              // pad octet: B is zero, addr dontcare
        int dh = tp / 3, dw = tp - dh*3;
        aoffB[s] = ((2*g*580) + (rowr + dh)*58 + (colb + dw)) * 16;
    }
    const int hq = q >> 1;
    const int wq = (q & 1) * 4;
    float lsum = 0.f, lsq = 0.f;

    __syncthreads();                      // wb/halo visible (also drains prefetch)
    bf16x8 bfrag[5];
    #pragma unroll
    for (int s = 0; s < 5; ++s)
        bfrag[s] = *(const bf16x8*)(wb + n*160 + s*32 + q*8);

    for (int hb = 0; hb < 7; ++hb) {
        __syncthreads();                  // waits DMA(hb) + prior-band LDS ops

        if (hb < 6) {                     // fire DMA for next band, other buffer
            float* dst = &xb[(hb + 1) & 1][0];
            const int msk = (hb + 1 == 6) ? mlast : mmid;
            const int go  = xbase + (hb + 1)*8*WW*CC;
            #pragma unroll
            for (int j = 0; j < 10; ++j)
                if (j < nj && ((msk >> j) & 1))
                    dma16(x + go + goff[j], (char*)dst + (wvu10 + j)*1024);
            if (hb + 1 == 6 && t < 224) { // zero row 9 (h=56 OOB) of that buffer
                int plane = t / 56;
                int col = t - plane*56 + 1;
                *(f32x4*)&dst[(plane*580 + 9*58 + col)*4] = (f32x4){0.f,0.f,0.f,0.f};
            }
        }

        const float* src = &xb[hb & 1][0];
        #pragma unroll 2
        for (int ct = 0; ct < 7; ++ct) {
            f32x4 acc = {0.f,0.f,0.f,0.f};
            #pragma unroll
            for (int s = 0; s < 5; ++s) {
                const char* p = (const char*)src + aoffB[s] + ct*128;
                f32x4 lo = *(const f32x4*)p;
                f32x4 hi = *(const f32x4*)(p + 9280);   // next ci4-plane
                // fp32 -> bf16 round-half-up (+0x8000, take hi16) + v_perm pack
                u32 a0 = __float_as_uint(lo[0]) + 0x8000u;
                u32 a1 = __float_as_uint(lo[1]) + 0x8000u;
                u32 a2 = __float_as_uint(lo[2]) + 0x8000u;
                u32 a3 = __float_as_uint(lo[3]) + 0x8000u;
                u32 a4 = __float_as_uint(hi[0]) + 0x8000u;
                u32 a5 = __float_as_uint(hi[1]) + 0x8000u;
                u32 a6 = __float_as_uint(hi[2]) + 0x8000u;
                u32 a7 = __float_as_uint(hi[3]) + 0x8000u;
                uint4 pk;
                pk.x = __builtin_amdgcn_perm(a1, a0, 0x07060302u);
                pk.y = __builtin_amdgcn_perm(a3, a2, 0x07060302u);
                pk.z = __builtin_amdgcn_perm(a5, a4, 0x07060302u);
                pk.w = __builtin_amdgcn_perm(a7, a6, 0x07060302u);
                bf16x8 af = __builtin_bit_cast(bf16x8, pk);
                acc = __builtin_amdgcn_mfma_f32_16x16x32_bf16(af, bfrag[s], acc, 0, 0, 0);
            }
            const int h = hb*8 + wv*2 + hq;
            const size_t base = (((size_t)(b*HH + h))*WW + ct*8 + wq)*CC + gp*16 + n;
            #pragma unroll
            for (int i = 0; i < 4; ++i) {
                float vv = acc[i];
                y[base + (size_t)i*CC] = __float2bfloat16(vv);
                lsum += vv;
                lsq  += vv * vv;
            }
        }
    }

    atomicAdd(&bsum[n], lsum);
    atomicAdd(&bsq[n],  lsq);
    __syncthreads();
    if (t < 16) {
        atomicAdd(&stats[gp*16 + t],       bsum[t]);
        atomicAdd(&stats[256 + gp*16 + t], bsq[t]);
    }
}

__global__ void k2_finalize(const float* __restrict__ stats,
                            const float* __restrict__ gamma,
                            const float* __restrict__ beta,
                            float* __restrict__ ss)
{
    int c = threadIdx.x;
    float inv_n = 1.f / (float)NPIX;
    float mean = stats[c] * inv_n;
    float var  = stats[256 + c] * inv_n - mean * mean;
    float scale = gamma[c] * rsqrtf(var + EPS);
    ss[c]       = scale;
    ss[256 + c] = beta[c] - mean * scale;   // conv bias cancels under BN
}

// Normalize+ReLU. Fixed channel-octet per thread, scale/shift in registers.
// Nontemporal stores keep the 103 MB out-stream from evicting y from L3.
__global__ __launch_bounds__(256) void k3_norm(
    const __hip_bfloat16* __restrict__ y, const float* __restrict__ ss,
    float* __restrict__ out)
{
    const int t   = threadIdx.x;
    const int oct = t & 31;               // channel octet
    const int pr  = t >> 5;               // pixel sub-index 0..7
    const int c0  = oct * 8;

    float4 sc0 = *(const float4*)(ss + c0);
    float4 sc1 = *(const float4*)(ss + c0 + 4);
    float4 sh0 = *(const float4*)(ss + 256 + c0);
    float4 sh1 = *(const float4*)(ss + 256 + c0 + 4);

    const uint4* yv = (const uint4*)y;
    const int px0 = blockIdx.x * 16 + pr;

    uint4 d[2];
    #pragma unroll
    for (int i = 0; i < 2; ++i)
        d[i] = yv[(size_t)(px0 + i*8)*32 + oct];

    #pragma unroll
    for (int i = 0; i < 2; ++i) {
        const int px = px0 + i*8;
        float f0 = __uint_as_float((d[i].x & 0xffffu) << 16);
        float f1 = __uint_as_float(d[i].x & 0xffff0000u);
        float f2 = __uint_as_float((d[i].y & 0xffffu) << 16);
        float f3 = __uint_as_float(d[i].y & 0xffff0000u);
        float f4 = __uint_as_float((d[i].z & 0xffffu) << 16);
        float f5 = __uint_as_float(d[i].z & 0xffff0000u);
        float f6 = __uint_as_float((d[i].w & 0xffffu) << 16);
        float f7 = __uint_as_float(d[i].w & 0xffff0000u);

        f32x4 o0, o1;
        o0[0] = fmaxf(0.f, f0 * sc0.x + sh0.x);
        o0[1] = fmaxf(0.f, f1 * sc0.y + sh0.y);
        o0[2] = fmaxf(0.f, f2 * sc0.z + sh0.z);
        o0[3] = fmaxf(0.f, f3 * sc0.w + sh0.w);
        o1[0] = fmaxf(0.f, f4 * sc1.x + sh1.x);
        o1[1] = fmaxf(0.f, f5 * sc1.y + sh1.y);
        o1[2] = fmaxf(0.f, f6 * sc1.z + sh1.z);
        o1[3] = fmaxf(0.f, f7 * sc1.w + sh1.w);

        f32x4* op = (f32x4*)out + (size_t)px*64 + oct*2;
        __builtin_nontemporal_store(o0, op);
        __builtin_nontemporal_store(o1, op + 1);
    }
}

extern "C" void kernel_launch(void* const* d_in, const int* in_sizes, int n_in,
                              void* d_out, int out_size, void* d_ws, size_t ws_size,
                              hipStream_t stream) {
    const float* x     = (const float*)d_in[0];
    const float* wgt   = (const float*)d_in[1];
    // d_in[2] = conv bias: cancels exactly under BN mean-subtraction -- unused
    const float* gamma = (const float*)d_in[3];
    const float* beta  = (const float*)d_in[4];
    float* out = (float*)d_out;

    float* stats = (float*)d_ws;                                 // 512 floats
    float* ss    = (float*)((char*)d_ws + 2048);                 // 512 floats
    __hip_bfloat16* y = (__hip_bfloat16*)((char*)d_ws + 4096);   // 25.69M bf16

    hipMemsetAsync(stats, 0, 2048, stream);
    k1_conv<<<dim3(16, BB), 256, 0, stream>>>(x, wgt, y, stats);
    k2_finalize<<<1, 256, 0, stream>>>(stats, gamma, beta, ss);
    k3_norm<<<NPIX/16, 256, 0, stream>>>(y, ss, out);
}

// Round 5
// 255.384 us; speedup vs baseline: 1.1335x; 1.1335x over previous
//
#include <hip/hip_runtime.h>
#include <hip/hip_bf16.h>

#define BB 32
#define HH 56
#define WW 56
#define CC 256
#define NPIX (BB*HH*WW)   // 100352
#define EPS 1e-5f

typedef short bf16x8 __attribute__((ext_vector_type(8)));   // 8 bf16 = 4 VGPRs
typedef float f32x4  __attribute__((ext_vector_type(4)));
typedef unsigned int u32;

#define ROWB 1872   // LDS row stride bytes: 58*32 padded; 1872%128=80 (odd*16)
                    // -> row r and r+1 cover complementary 16-bank sets: 2-way, free

__device__ __forceinline__ unsigned short f2bf(float f) {
    __hip_bfloat16 h = __float2bfloat16(f);
    return *reinterpret_cast<unsigned short*>(&h);
}

// ws layout:
//   float stats[512]   : byte 0      (sum[256], sumsq[256]) -- zeroed by memsetAsync
//   bf16  y[B*H*W*256] : byte 4096   (51.4 MB)

// Grouped conv via bf16 MFMA. Block = (group-pair, batch, row-half).
// Persistent over 4 (resp 3) bands of 8 output rows; double-buffered LDS with
// REGISTER prefetch: global loads for band i+1 issue before compute of band i
// (coalesced: 4 lanes per 64B line, 1KB per inst), fp32->bf16 conversion at
// staging, compute reads one ds_read_b128 per MFMA fragment.
__global__ __launch_bounds__(256, 3) void k1_conv(
    const float* __restrict__ x, const float* __restrict__ wgt,
    __hip_bfloat16* __restrict__ y, float* __restrict__ stats)
{
    __shared__ __align__(16) unsigned char xbuf[2][10*ROWB];  // bf16 tiles, 2x18720 B
    __shared__ unsigned short wb[16*160];                     // B-frag-major weights
    __shared__ float bsum[16], bsq[16];

    const int gp   = blockIdx.x;            // group pair 0..15 (out-ch gp*16..+16)
    const int b    = blockIdx.y;            // batch image
    const int hz   = blockIdx.z;            // row half: 0 -> bands 0..3, 1 -> 4..6
    const int t    = threadIdx.x;
    const int lane = t & 63;
    const int wv   = t >> 6;
    const int k0h  = hz*4, nb = 4 - hz;

    if (t < 16) { bsum[t] = 0.f; bsq[t] = 0.f; }

    // ---- weights (once per block): wb[n*160+kk], kk = g*80+tap*8+ci
    {
        const int n  = t >> 4;
        const int kq = t & 15;
        #pragma unroll
        for (int j = 0; j < 10; ++j) {
            const int kk = kq + j*16;
            const int g  = (kk >= 80);
            const int r  = kk - g*80;
            const int tap = r >> 3, ci = r & 7;
            unsigned short val = 0;
            if (tap < 9 && (n >> 3) == g)
                val = f2bf(wgt[(tap*8 + ci)*CC + gp*16 + n]);
            wb[n*160 + kk] = val;
        }
    }

    // ---- staging geometry: slot i = j*256+t over 4 ci4-chunks x 580 (row,col)
    int goff[10], soff[10];
    int mfull = 0, mfirst = 0, mlast = 0;   // per-j validity masks (per lane)
    #pragma unroll
    for (int j = 0; j < 10; ++j) {
        const int i   = j*256 + t;
        const int ci4 = i & 3;
        const int cq  = i >> 2;
        const int row = cq / 58;            // magic-mul
        const int col = cq - row*58;
        goff[j] = ((row - 1)*WW + (col - 1))*CC + ci4*4;    // band-0 basis
        soff[j] = row*ROWB + col*32 + ci4*8;
        const bool ok = (i < 2320) && (col >= 1) && (col <= 56);
        if (ok) {
            mfull |= 1 << j;
            if (row != 0) mfirst |= 1 << j;   // band 0: in-row -1 OOB
            if (row != 9) mlast  |= 1 << j;   // band 6: in-row 56 OOB
        }
    }
    const int xbase = b*HH*WW*CC + gp*16;

    // ---- fragment geometry
    const int n    = lane & 15;             // out-ch within pair / C col
    const int q    = lane >> 4;             // quad
    const int m    = lane & 15;             // A row = pixel in 2x8 tile
    const int rowr = wv*2 + (m >> 3);       // output row within band (0..7)
    const int colb = m & 7;
    int aoffB[5];
    #pragma unroll
    for (int s = 0; s < 5; ++s) {
        int o  = s*4 + q;                   // octet 0..19
        int g  = (o >= 10);
        int tp = o - g*10;
        if (tp == 9) tp = 0;                // pad octet: B is zero, addr dontcare
        int dh = tp / 3, dw = tp - dh*3;
        aoffB[s] = (rowr + dh)*ROWB + (colb + dw)*32 + g*16;
    }
    const int hq = q >> 1;
    const int wq = (q & 1) * 4;

    // ---- prefetch band k0h into regs, convert+write buf0
    float4 v[10];
    {
        const float* gx = x + xbase + k0h*8*WW*CC;
        const int msk = (k0h == 0) ? mfirst : mfull;
        #pragma unroll
        for (int j = 0; j < 10; ++j) {
            v[j] = make_float4(0.f, 0.f, 0.f, 0.f);
            if ((msk >> j) & 1) v[j] = *(const float4*)(gx + goff[j]);
        }
    }
    #pragma unroll
    for (int j = 0; j < 10; ++j) {
        if (j*256 + t < 2320) {
            u32 a0 = __float_as_uint(v[j].x) + 0x8000u;
            u32 a1 = __float_as_uint(v[j].y) + 0x8000u;
            u32 a2 = __float_as_uint(v[j].z) + 0x8000u;
            u32 a3 = __float_as_uint(v[j].w) + 0x8000u;
            uint2 pk;
            pk.x = __builtin_amdgcn_perm(a1, a0, 0x07060302u);
            pk.y = __builtin_amdgcn_perm(a3, a2, 0x07060302u);
            *(uint2*)(&xbuf[0][0] + soff[j]) = pk;
        }
    }
    __syncthreads();

    bf16x8 bfrag[5];
    #pragma unroll
    for (int s = 0; s < 5; ++s)
        bfrag[s] = *(const bf16x8*)(wb + n*160 + s*32 + q*8);

    float lsum = 0.f, lsq = 0.f;

    for (int kk = 0; kk < nb; ++kk) {
        const int k = k0h + kk;
        const unsigned char* cur = &xbuf[kk & 1][0];
        unsigned char* nxt = &xbuf[(kk & 1) ^ 1][0];
        const bool more = (kk + 1 < nb);

        // (A) issue next band's global loads early (hidden under compute)
        if (more) {
            const float* gx = x + xbase + (k + 1)*8*WW*CC;
            const int msk = (k + 1 == 6) ? mlast : mfull;
            #pragma unroll
            for (int j = 0; j < 10; ++j) {
                v[j] = make_float4(0.f, 0.f, 0.f, 0.f);
                if ((msk >> j) & 1) v[j] = *(const float4*)(gx + goff[j]);
            }
        }

        // (B) compute band k from cur
        #pragma unroll
        for (int ct = 0; ct < 7; ++ct) {
            f32x4 acc = {0.f, 0.f, 0.f, 0.f};
            #pragma unroll
            for (int s = 0; s < 5; ++s) {
                bf16x8 af = *(const bf16x8*)(cur + aoffB[s] + ct*256);
                acc = __builtin_amdgcn_mfma_f32_16x16x32_bf16(af, bfrag[s], acc, 0, 0, 0);
            }
            const int h = k*8 + wv*2 + hq;
            const size_t base = (((size_t)(b*HH + h))*WW + ct*8 + wq)*CC + gp*16 + n;
            #pragma unroll
            for (int i = 0; i < 4; ++i) {
                float vv = acc[i];
                y[base + (size_t)i*CC] = __float2bfloat16(vv);
                lsum += vv;
                lsq  += vv * vv;
            }
        }

        // (C) convert + stage next band into the other buffer
        if (more) {
            #pragma unroll
            for (int j = 0; j < 10; ++j) {
                if (j*256 + t < 2320) {
                    u32 a0 = __float_as_uint(v[j].x) + 0x8000u;
                    u32 a1 = __float_as_uint(v[j].y) + 0x8000u;
                    u32 a2 = __float_as_uint(v[j].z) + 0x8000u;
                    u32 a3 = __float_as_uint(v[j].w) + 0x8000u;
                    uint2 pk;
                    pk.x = __builtin_amdgcn_perm(a1, a0, 0x07060302u);
                    pk.y = __builtin_amdgcn_perm(a3, a2, 0x07060302u);
                    *(uint2*)(nxt + soff[j]) = pk;
                }
            }
        }
        // (D) one barrier per band: seals cur-reads and nxt-writes
        __syncthreads();
    }

    atomicAdd(&bsum[n], lsum);
    atomicAdd(&bsq[n],  lsq);
    __syncthreads();
    if (t < 16) {
        atomicAdd(&stats[gp*16 + t],       bsum[t]);
        atomicAdd(&stats[256 + gp*16 + t], bsq[t]);
    }
}

// Fused finalize + normalize + ReLU. Preamble computes scale/shift from raw
// stats (2KB, L2-hot) per block; main loop: fixed channel-octet per thread,
// scale/shift in registers, NT stores for the 103 MB out stream.
__global__ __launch_bounds__(256) void k3_norm(
    const __hip_bfloat16* __restrict__ y, const float* __restrict__ stats,
    const float* __restrict__ gamma, const float* __restrict__ beta,
    float* __restrict__ out)
{
    __shared__ float lss[512];
    const int t = threadIdx.x;
    {
        const float inv_n = 1.f / (float)NPIX;
        float mean = stats[t] * inv_n;
        float var  = stats[256 + t] * inv_n - mean * mean;
        float sc   = gamma[t] * rsqrtf(var + EPS);
        lss[t]       = sc;
        lss[256 + t] = beta[t] - mean * sc;   // conv bias cancels under BN
    }
    __syncthreads();

    const int oct = t & 31;               // channel octet
    const int pr  = t >> 5;               // pixel sub-index 0..7
    const int c0  = oct * 8;

    float4 sc0 = *(const float4*)(lss + c0);
    float4 sc1 = *(const float4*)(lss + c0 + 4);
    float4 sh0 = *(const float4*)(lss + 256 + c0);
    float4 sh1 = *(const float4*)(lss + 256 + c0 + 4);

    const uint4* yv = (const uint4*)y;
    const int px0 = blockIdx.x * 16 + pr;

    uint4 d[2];
    #pragma unroll
    for (int i = 0; i < 2; ++i)
        d[i] = yv[(size_t)(px0 + i*8)*32 + oct];

    #pragma unroll
    for (int i = 0; i < 2; ++i) {
        const int px = px0 + i*8;
        float f0 = __uint_as_float((d[i].x & 0xffffu) << 16);
        float f1 = __uint_as_float(d[i].x & 0xffff0000u);
        float f2 = __uint_as_float((d[i].y & 0xffffu) << 16);
        float f3 = __uint_as_float(d[i].y & 0xffff0000u);
        float f4 = __uint_as_float((d[i].z & 0xffffu) << 16);
        float f5 = __uint_as_float(d[i].z & 0xffff0000u);
        float f6 = __uint_as_float((d[i].w & 0xffffu) << 16);
        float f7 = __uint_as_float(d[i].w & 0xffff0000u);

        f32x4 o0, o1;
        o0[0] = fmaxf(0.f, f0 * sc0.x + sh0.x);
        o0[1] = fmaxf(0.f, f1 * sc0.y + sh0.y);
        o0[2] = fmaxf(0.f, f2 * sc0.z + sh0.z);
        o0[3] = fmaxf(0.f, f3 * sc0.w + sh0.w);
        o1[0] = fmaxf(0.f, f4 * sc1.x + sh1.x);
        o1[1] = fmaxf(0.f, f5 * sc1.y + sh1.y);
        o1[2] = fmaxf(0.f, f6 * sc1.z + sh1.z);
        o1[3] = fmaxf(0.f, f7 * sc1.w + sh1.w);

        f32x4* op = (f32x4*)out + (size_t)px*64 + oct*2;
        __builtin_nontemporal_store(o0, op);
        __builtin_nontemporal_store(o1, op + 1);
    }
}

extern "C" void kernel_launch(void* const* d_in, const int* in_sizes, int n_in,
                              void* d_out, int out_size, void* d_ws, size_t ws_size,
                              hipStream_t stream) {
    const float* x     = (const float*)d_in[0];
    const float* wgt   = (const float*)d_in[1];
    // d_in[2] = conv bias: cancels exactly under BN mean-subtraction -- unused
    const float* gamma = (const float*)d_in[3];
    const float* beta  = (const float*)d_in[4];
    float* out = (float*)d_out;

    float* stats = (float*)d_ws;                                 // 512 floats
    __hip_bfloat16* y = (__hip_bfloat16*)((char*)d_ws + 4096);   // 25.69M bf16

    hipMemsetAsync(stats, 0, 2048, stream);
    k1_conv<<<dim3(16, BB, 2), 256, 0, stream>>>(x, wgt, y, stats);
    k3_norm<<<NPIX/16, 256, 0, stream>>>(y, stats, gamma, beta, out);
}

// Round 6
// 250.375 us; speedup vs baseline: 1.1562x; 1.0200x over previous
//
#include <hip/hip_runtime.h>
#include <hip/hip_bf16.h>

#define BB 32
#define HH 56
#define WW 56
#define CC 256
#define NPIX (BB*HH*WW)   // 100352
#define EPS 1e-5f

typedef short bf16x8 __attribute__((ext_vector_type(8)));   // 8 bf16 = 4 VGPRs
typedef float f32x4  __attribute__((ext_vector_type(4)));
typedef unsigned int u32;

// LDS x-tile geometry: [row 0..5][col 0..29][oct 0..15][8 bf16]
// col stride 272 B (16 oct * 16 B + 16 pad; 272 % 128 = 16 -> adjacent cols
// rotate 4 banks), row stride 30*272 = 8160 (%128 = 96 -> rotates too).
#define COLB 272
#define ROWB (30*COLB)    // 8160

__device__ __forceinline__ unsigned short f2bf(float f) {
    __hip_bfloat16 h = __float2bfloat16(f);
    return *reinterpret_cast<unsigned short*>(&h);
}

// ws layout:
//   float stats[512]   : byte 0      (sum[256], sumsq[256]) -- zeroed by memsetAsync
//   bf16  y[B*H*W*256] : byte 4096   (51.4 MB)

// Grouped conv via bf16 MFMA. Block = (col-half, ch-half, 4-row band, batch),
// 512 threads. KEY FIX vs R2-R5: the block stages 128 CONTIGUOUS channels, so
// every global fetch is a dense 512-B run (vs 64-B strided slices that
// thrashed DRAM rows and capped HBM at ~1.3 TB/s). One barrier per block;
// pipelining comes from 2 blocks/CU (16 waves) + dispatch overlap.
// Wave w owns group-pair w (16 out-ch): K packed [g0 taps|pad][g1 taps|pad]
// = 160 -> 5 x mfma_f32_16x16x32_bf16 with block-diagonal B; A-frag = one
// tap's 8 in-ch read as a single ds_read_b128 from the tile.
__global__ __launch_bounds__(512, 4) void k1_conv(
    const float* __restrict__ x, const float* __restrict__ wgt,
    __hip_bfloat16* __restrict__ y, float* __restrict__ stats)
{
    __shared__ __align__(16) unsigned char xs[6*ROWB];   // 48960 B bf16 tile
    __shared__ float bsum[128], bsq[128];

    const int cq   = blockIdx.x & 1;         // col half (28 output cols)
    const int chh  = blockIdx.x >> 1;        // channel half (128 ch)
    const int hb   = blockIdx.y;             // row band 0..13 (4 output rows)
    const int b    = blockIdx.z;
    const int t    = threadIdx.x;
    const int lane = t & 63;
    const int w    = t >> 6;                 // wave id = gp-pair 0..7
    const int r0   = hb*4, c0 = cq*28;
    const int chbase = chh*128;

    if (t < 128) { bsum[t] = 0.f; bsq[t] = 0.f; }

    // ---- stage x tile: 180 px * 16 octets = 2880 jobs, 32 B (8 ch) each.
    // Per inst the wave touches 512-B-dense pixel slices -> full DRAM bursts.
    #pragma unroll
    for (int jc = 0; jc < 2; ++jc) {
        float4 a[3], c[3];
        int so[3], iv[3];
        #pragma unroll
        for (int j = 0; j < 3; ++j) {
            const int i   = (jc*3 + j)*512 + t;
            const int oct = i & 15;
            const int pix = i >> 4;              // < 192 (valid < 180)
            const int row = pix / 30;
            const int col = pix - row*30;
            const int gh  = r0 - 1 + row;
            const int gw  = c0 - 1 + col;
            so[j] = row*ROWB + col*COLB + oct*16;
            iv[j] = (i < 2880);
            const bool ok = iv[j] && ((unsigned)gh < HH) && ((unsigned)gw < WW);
            const float* p = x + ((size_t)((b*HH + gh)*WW + gw))*CC + chbase + oct*8;
            a[j] = ok ? *(const float4*)p       : make_float4(0.f,0.f,0.f,0.f);
            c[j] = ok ? *(const float4*)(p + 4) : make_float4(0.f,0.f,0.f,0.f);
        }
        #pragma unroll
        for (int j = 0; j < 3; ++j) {
            if (iv[j]) {
                u32 a0 = __float_as_uint(a[j].x) + 0x8000u;
                u32 a1 = __float_as_uint(a[j].y) + 0x8000u;
                u32 a2 = __float_as_uint(a[j].z) + 0x8000u;
                u32 a3 = __float_as_uint(a[j].w) + 0x8000u;
                u32 a4 = __float_as_uint(c[j].x) + 0x8000u;
                u32 a5 = __float_as_uint(c[j].y) + 0x8000u;
                u32 a6 = __float_as_uint(c[j].z) + 0x8000u;
                u32 a7 = __float_as_uint(c[j].w) + 0x8000u;
                uint4 pk;
                pk.x = __builtin_amdgcn_perm(a1, a0, 0x07060302u);
                pk.y = __builtin_amdgcn_perm(a3, a2, 0x07060302u);
                pk.z = __builtin_amdgcn_perm(a5, a4, 0x07060302u);
                pk.w = __builtin_amdgcn_perm(a7, a6, 0x07060302u);
                *(uint4*)(xs + so[j]) = pk;
            }
        }
    }

    // ---- B fragments: direct gathered loads from global (36 KB, L2-hot).
    // wgt[(tap*8+ci)*256 + ch]; lane (n,q): K-step s -> octet o = s*4+q.
    const int n = lane & 15;                 // B col / out-ch within pair
    const int q = lane >> 4;                 // quad
    bf16x8 bfrag[5];
    #pragma unroll
    for (int s = 0; s < 5; ++s) {
        const int o  = s*4 + q;
        const int g  = (o >= 10);
        const int tp = o - g*10;
        const int tp0 = (tp == 9) ? 0 : tp;  // pad octet -> safe addr
        const bool val = (tp < 9) && ((n >> 3) == g);
        const float* wp = wgt + tp0*8*CC + chbase + w*16 + n;
        #pragma unroll
        for (int ci = 0; ci < 8; ++ci) {
            float f = val ? wp[ci*CC] : 0.f;
            bfrag[s][ci] = (short)f2bf(f);
        }
    }

    // ---- A-fragment LDS offsets: pixel m=(pr,pc) in 4x4 tile, tap from o
    const int pr = (lane & 15) >> 2;
    const int pc = lane & 3;
    int aoff[5];
    #pragma unroll
    for (int s = 0; s < 5; ++s) {
        const int o  = s*4 + q;
        const int g  = (o >= 10);
        int tp = o - g*10;
        if (tp == 9) tp = 0;                 // pad: B is zero, addr dontcare
        const int dh = tp / 3, dw = tp - dh*3;
        aoff[s] = (pr + dh)*ROWB + (pc + dw)*COLB + (2*w + g)*16;
    }

    __syncthreads();

    const int cb = chbase + w*16 + n;        // this lane's output channel
    float lsum = 0.f, lsq = 0.f;

    #pragma unroll
    for (int ct = 0; ct < 7; ++ct) {         // 7 tiles of 4x4 pixels
        f32x4 acc = {0.f, 0.f, 0.f, 0.f};
        #pragma unroll
        for (int s = 0; s < 5; ++s) {
            bf16x8 af = *(const bf16x8*)(xs + aoff[s] + ct*(4*COLB));
            acc = __builtin_amdgcn_mfma_f32_16x16x32_bf16(af, bfrag[s], acc, 0, 0, 0);
        }
        // C layout: col = lane&15 = n, row = q*4 + i = pixel -> (pr=q, pc=i)
        const int h = r0 + q;
        const size_t base = ((size_t)((b*HH + h)*WW + c0 + ct*4))*CC + cb;
        #pragma unroll
        for (int i = 0; i < 4; ++i) {
            float vv = acc[i];
            y[base + (size_t)i*CC] = __float2bfloat16(vv);
            lsum += vv;
            lsq  += vv * vv;
        }
    }

    atomicAdd(&bsum[w*16 + n], lsum);
    atomicAdd(&bsq[w*16 + n],  lsq);
    __syncthreads();
    if (t < 128) {
        atomicAdd(&stats[chbase + t],       bsum[t]);
        atomicAdd(&stats[256 + chbase + t], bsq[t]);
    }
}

// Fused finalize + normalize + ReLU. Preamble computes scale/shift from raw
// stats (2 KB, L2-hot); main loop: fixed channel-octet per thread, scale/
// shift in registers, NT stores for the 103 MB out stream.
__global__ __launch_bounds__(256) void k3_norm(
    const __hip_bfloat16* __restrict__ y, const float* __restrict__ stats,
    const float* __restrict__ gamma, const float* __restrict__ beta,
    float* __restrict__ out)
{
    __shared__ float lss[512];
    const int t = threadIdx.x;
    {
        const float inv_n = 1.f / (float)NPIX;
        float mean = stats[t] * inv_n;
        float var  = stats[256 + t] * inv_n - mean * mean;
        float sc   = gamma[t] * rsqrtf(var + EPS);
        lss[t]       = sc;
        lss[256 + t] = beta[t] - mean * sc;   // conv bias cancels under BN
    }
    __syncthreads();

    const int oct = t & 31;               // channel octet
    const int pr  = t >> 5;               // pixel sub-index 0..7
    const int c0  = oct * 8;

    float4 sc0 = *(const float4*)(lss + c0);
    float4 sc1 = *(const float4*)(lss + c0 + 4);
    float4 sh0 = *(const float4*)(lss + 256 + c0);
    float4 sh1 = *(const float4*)(lss + 256 + c0 + 4);

    const uint4* yv = (const uint4*)y;
    const int px0 = blockIdx.x * 16 + pr;

    uint4 d[2];
    #pragma unroll
    for (int i = 0; i < 2; ++i)
        d[i] = yv[(size_t)(px0 + i*8)*32 + oct];

    #pragma unroll
    for (int i = 0; i < 2; ++i) {
        const int px = px0 + i*8;
        float f0 = __uint_as_float((d[i].x & 0xffffu) << 16);
        float f1 = __uint_as_float(d[i].x & 0xffff0000u);
        float f2 = __uint_as_float((d[i].y & 0xffffu) << 16);
        float f3 = __uint_as_float(d[i].y & 0xffff0000u);
        float f4 = __uint_as_float((d[i].z & 0xffffu) << 16);
        float f5 = __uint_as_float(d[i].z & 0xffff0000u);
        float f6 = __uint_as_float((d[i].w & 0xffffu) << 16);
        float f7 = __uint_as_float(d[i].w & 0xffff0000u);

        f32x4 o0, o1;
        o0[0] = fmaxf(0.f, f0 * sc0.x + sh0.x);
        o0[1] = fmaxf(0.f, f1 * sc0.y + sh0.y);
        o0[2] = fmaxf(0.f, f2 * sc0.z + sh0.z);
        o0[3] = fmaxf(0.f, f3 * sc0.w + sh0.w);
        o1[0] = fmaxf(0.f, f4 * sc1.x + sh1.x);
        o1[1] = fmaxf(0.f, f5 * sc1.y + sh1.y);
        o1[2] = fmaxf(0.f, f6 * sc1.z + sh1.z);
        o1[3] = fmaxf(0.f, f7 * sc1.w + sh1.w);

        f32x4* op = (f32x4*)out + (size_t)px*64 + oct*2;
        __builtin_nontemporal_store(o0, op);
        __builtin_nontemporal_store(o1, op + 1);
    }
}

extern "C" void kernel_launch(void* const* d_in, const int* in_sizes, int n_in,
                              void* d_out, int out_size, void* d_ws, size_t ws_size,
                              hipStream_t stream) {
    const float* x     = (const float*)d_in[0];
    const float* wgt   = (const float*)d_in[1];
    // d_in[2] = conv bias: cancels exactly under BN mean-subtraction -- unused
    const float* gamma = (const float*)d_in[3];
    const float* beta  = (const float*)d_in[4];
    float* out = (float*)d_out;

    float* stats = (float*)d_ws;                                 // 512 floats
    __hip_bfloat16* y = (__hip_bfloat16*)((char*)d_ws + 4096);   // 25.69M bf16

    hipMemsetAsync(stats, 0, 2048, stream);
    k1_conv<<<dim3(4, 14, BB), 512, 0, stream>>>(x, wgt, y, stats);
    k3_norm<<<NPIX/16, 256, 0, stream>>>(y, stats, gamma, beta, out);
}